// Round 9
// baseline (89.971 us; speedup 1.0000x reference)
//
#include <hip/hip_runtime.h>
#include <math.h>

typedef float v2 __attribute__((ext_vector_type(2)));

#define SCALE 1073741824.0   // 2^30 fixed-point for deterministic atomic sum
#define NPIX 12582912.0      // 16*3*512*512
#define C1f 1e-4f
#define C2f 9e-4f

#define IMG_STR  528         // floats per image row in LDS (8 pad | 512 | 8 pad)
#define SLOT_STR 1056        // floats per slot (2 images)

struct Wts {
    float w[11];   // V-pass weights
    v2 hp[12];     // H-pass pair weights for element e=j+1: (w[j]|0, w[j-1]|0)
};

__device__ __forceinline__ v2 sp(float x) { v2 r; r.x = x; r.y = x; return r; }
__device__ __forceinline__ v2 f2(v2 a, v2 b, v2 c) {
    return __builtin_elementwise_fma(a, b, c);
}

// H-blur of row X (in LDS slot SLR) into ring slot PH. Zero-padded data ->
// no column masks needed. All indices literal.
#define HPM(PH, SLR) do {                                                   \
    const float* rp_ = &rowbuf[(SLR) * SLOT_STR] + lds_rd;                  \
    v2 ca_[7], cb_[7];                                                      \
    _Pragma("unroll") for (int k_ = 0; k_ < 7; ++k_) {                      \
        ca_[k_] = *(const v2*)(rp_ + 2 * k_);                               \
        cb_[k_] = *(const v2*)(rp_ + IMG_STR + 2 * k_);                     \
    }                                                                       \
    v2 uS_[7], uD_[7], uP_[7], uM_[7];                                      \
    _Pragma("unroll") for (int k_ = 0; k_ < 7; ++k_) {                      \
        uS_[k_] = ca_[k_] + cb_[k_];                                        \
        uD_[k_] = ca_[k_] - cb_[k_];                                        \
        uP_[k_] = uS_[k_] * uS_[k_];                                        \
        uM_[k_] = uD_[k_] * uD_[k_];                                        \
    }                                                                       \
    v2 hS_ = sp(0.f), hD_ = sp(0.f), hP_ = sp(0.f), hM_ = sp(0.f);          \
    _Pragma("unroll") for (int j_ = 0; j_ < 12; ++j_) {                     \
        const int e_ = j_ + 1, ch_ = e_ >> 1;                               \
        v2 bS_, bD_, bP_, bM_;                                              \
        if (e_ & 1) { bS_ = sp(uS_[ch_].y); bD_ = sp(uD_[ch_].y);           \
                      bP_ = sp(uP_[ch_].y); bM_ = sp(uM_[ch_].y); }         \
        else        { bS_ = sp(uS_[ch_].x); bD_ = sp(uD_[ch_].x);           \
                      bP_ = sp(uP_[ch_].x); bM_ = sp(uM_[ch_].x); }         \
        hS_ = f2(W.hp[j_], bS_, hS_); hD_ = f2(W.hp[j_], bD_, hD_);         \
        hP_ = f2(W.hp[j_], bP_, hP_); hM_ = f2(W.hp[j_], bM_, hM_);         \
    }                                                                       \
    rS[PH] = hS_; rD[PH] = hD_; rP[PH] = hP_; rM[PH] = hM_; } while (0)

// V-blur + SSIM for the output whose 11 window rows sit in ring slots
// (PH+1..PH+11)%12 (slot PH is the dead slot).
#define VOUTM(PH, vmval) do {                                               \
    v2 S_ = sp(0.f), D_ = sp(0.f), P_ = sp(0.f), M_ = sp(0.f);              \
    _Pragma("unroll") for (int k_ = 0; k_ < 11; ++k_) {                     \
        const int q_ = ((PH) + 1 + k_) % 12;                                \
        const v2 wk_ = sp(W.w[k_]);                                         \
        S_ = f2(wk_, rS[q_], S_); D_ = f2(wk_, rD[q_], D_);                 \
        P_ = f2(wk_, rP[q_], P_); M_ = f2(wk_, rM[q_], M_);                 \
    }                                                                       \
    const v2 ss_ = S_ * S_, dd_ = D_ * D_;                                  \
    const v2 mu12_  = (ss_ - dd_) * sp(0.25f);                              \
    const v2 musq_  = (ss_ + dd_) * sp(0.5f);                               \
    const v2 sig12_ = (P_ - M_) * sp(0.25f) - mu12_;                        \
    const v2 sigsm_ = (P_ + M_) * sp(0.5f) - musq_;                         \
    const v2 num_ = (sp(2.f) * mu12_ + sp(C1f)) * (sp(2.f) * sig12_ + sp(C2f)); \
    const v2 den_ = (musq_ + sp(C1f)) * (sigsm_ + sp(C2f));                 \
    v2 r_;                                                                  \
    r_.x = __builtin_amdgcn_rcpf(den_.x);                                   \
    r_.y = __builtin_amdgcn_rcpf(den_.y);                                   \
    r_ = r_ * (sp(2.f) - den_ * r_);                                        \
    loc = f2(num_ * sp(vmval), r_, loc); } while (0)

// One step (scur = runtime step index; PH/SLR/SLW literal):
//  1) ds_write row scur-4+r0 (staged last step, row-masked)
//  2) issue global load of row scur-3+r0 (consumed in 2 steps)
//  3) H-blur row r0-5+scur from LDS slot SLR into ring[PH]
//  4) optional V-output, then fence + barrier
#define STEP(PH, SLR, SLW, scur, DOV) do {                                  \
    const int grw_ = r0 - 4 + (scur);                                       \
    const float mw_ = ((unsigned)grw_ < 512u) ? 1.f : 0.f;                  \
    float4 w4_;                                                             \
    w4_.x = sreg.x * mw_; w4_.y = sreg.y * mw_;                             \
    w4_.z = sreg.z * mw_; w4_.w = sreg.w * mw_;                             \
    *(float4*)(&rowbuf[(SLW) * SLOT_STR] + lds_wr) = w4_;                   \
    {   const int grl_ = r0 - 3 + (scur);                                   \
        const int rc_ = grl_ < 0 ? 0 : (grl_ > 511 ? 511 : grl_);           \
        sreg = *(const float4*)(sbase + rc_ * 512 + scol);                  \
    }                                                                       \
    HPM(PH, SLR);                                                           \
    if (DOV) {                                                              \
        const float vm_ = (r0 + (scur) - 11 < 512) ? 1.f : 0.f;             \
        VOUTM(PH, vm_);                                                     \
    }                                                                       \
    __builtin_amdgcn_sched_barrier(0);                                      \
    __syncthreads();                                                        \
} while (0)

__global__ __launch_bounds__(256, 3) void ssim_main(
    const float* __restrict__ img1, const float* __restrict__ img2,
    unsigned long long* __restrict__ acc, Wts W)
{
    __shared__ float rowbuf[2 * SLOT_STR];
    __shared__ float red[4];

    const int tid = threadIdx.x;
    const int lane = tid & 63;
    const int wv = tid >> 6;
    const int r0 = blockIdx.x * 36;            // 15 strips of 36 output rows
    const int plane = blockIdx.y;              // 48 planes
    // this thread computes output cols 2*tid, 2*tid+1 (block = full width)

    const float* baseA = img1 + (size_t)plane * 262144;
    const float* baseB = img2 + (size_t)plane * 262144;

    // staging role: threads 0-127 stage image A, 128-255 image B; 4 floats each
    const int simg = tid >> 7;
    const int scol = 4 * (tid & 127);
    const float* sbase = simg ? baseB : baseA;
    const int lds_wr = simg * IMG_STR + 8 + scol;   // float index within slot
    const int lds_rd = 2 + 2 * tid;                 // window start (col-6), img A

    // zero the pad regions once (floats [0,8) and [520,528) per slot/img)
    if (tid < 32) {
        const int s_ = tid >> 4, rest = tid & 15;
        const int i_ = rest >> 3, p_ = rest & 7;
        rowbuf[s_ * SLOT_STR + i_ * IMG_STR + p_] = 0.f;
        rowbuf[s_ * SLOT_STR + i_ * IMG_STR + 520 + p_] = 0.f;
    }

    v2 rS[12], rD[12], rP[12], rM[12];         // 12-slot register ring
    v2 loc = sp(0.f);
    float4 sreg;

    // ---- pre-stage: row r0-5 -> LDS slot 1; preload row r0-4 into sreg ----
    {
        const int gr_ = r0 - 5;                       // may be -5..; never >511
        const float m_ = ((unsigned)gr_ < 512u) ? 1.f : 0.f;
        const int rc_ = gr_ < 0 ? 0 : gr_;
        const float4 t_ = *(const float4*)(sbase + rc_ * 512 + scol);
        float4 w_;
        w_.x = t_.x * m_; w_.y = t_.y * m_; w_.z = t_.z * m_; w_.w = t_.w * m_;
        *(float4*)(&rowbuf[1 * SLOT_STR] + lds_wr) = w_;
    }
    {
        const int gr_ = r0 - 4;
        const int rc_ = gr_ < 0 ? 0 : gr_;
        sreg = *(const float4*)(sbase + rc_ * 512 + scol);
    }
    __syncthreads();

    // ---- prologue: steps 0..10 fill ring slots 0..10 (no outputs) ----
    STEP(0, 1, 0, 0, 0);  STEP(1, 0, 1, 1, 0);  STEP(2, 1, 0, 2, 0);
    STEP(3, 0, 1, 3, 0);  STEP(4, 1, 0, 4, 0);  STEP(5, 0, 1, 5, 0);
    STEP(6, 1, 0, 6, 0);  STEP(7, 0, 1, 7, 0);  STEP(8, 1, 0, 8, 0);
    STEP(9, 0, 1, 9, 0);  STEP(10, 1, 0, 10, 0);

    // ---- main: 36 output steps as 3 x 12 literal-phase bodies ----
    for (int b_ = 0; b_ < 3; ++b_) {
        const int sb = 11 + 12 * b_;
        STEP(11, 0, 1, sb + 0, 1);  STEP(0, 1, 0, sb + 1, 1);
        STEP(1, 0, 1, sb + 2, 1);   STEP(2, 1, 0, sb + 3, 1);
        STEP(3, 0, 1, sb + 4, 1);   STEP(4, 1, 0, sb + 5, 1);
        STEP(5, 0, 1, sb + 6, 1);   STEP(6, 1, 0, sb + 7, 1);
        STEP(7, 0, 1, sb + 8, 1);   STEP(8, 1, 0, sb + 9, 1);
        STEP(9, 0, 1, sb + 10, 1);  STEP(10, 1, 0, sb + 11, 1);
    }

    // ---- reduction -> fixed-point global atomic ----
    float l = loc.x + loc.y;
#pragma unroll
    for (int o2 = 32; o2; o2 >>= 1)
        l += __shfl_down(l, o2, 64);
    if (lane == 0) red[wv] = l;
    __syncthreads();
    if (tid == 0) {
        const float bs = red[0] + red[1] + red[2] + red[3];
        const unsigned long long q =
            (unsigned long long)__double2ll_rn((double)bs * SCALE);
        atomicAdd(acc, q);
    }
}

__global__ void ssim_final(const unsigned long long* __restrict__ acc,
                           float* __restrict__ out)
{
    if (threadIdx.x == 0)
        out[0] = (float)((double)(*acc) * (1.0 / SCALE) / NPIX);
}

extern "C" void kernel_launch(void* const* d_in, const int* in_sizes, int n_in,
                              void* d_out, int out_size, void* d_ws, size_t ws_size,
                              hipStream_t stream) {
    const float* img1 = (const float*)d_in[0];
    const float* img2 = (const float*)d_in[1];
    float* out = (float*)d_out;
    unsigned long long* acc = (unsigned long long*)d_ws;

    double g[11], ssum = 0.0;
    for (int i = 0; i < 11; ++i) {
        const double d = (double)(i - 5);
        g[i] = exp(-(d * d) / 4.5);
        ssum += g[i];
    }
    Wts W;
    for (int i = 0; i < 11; ++i) W.w[i] = (float)(g[i] / ssum);
    for (int j = 0; j < 12; ++j) {
        v2 p;
        p.x = (j <= 10) ? W.w[j] : 0.f;      // out0 weight for element j+1
        p.y = (j >= 1) ? W.w[j - 1] : 0.f;   // out1 weight for element j+1
        W.hp[j] = p;
    }

    hipMemsetAsync(d_ws, 0, sizeof(unsigned long long), stream);
    ssim_main<<<dim3(15, 48), 256, 0, stream>>>(img1, img2, acc, W);
    ssim_final<<<1, 64, 0, stream>>>(acc, out);
}